// Round 7
// baseline (484.121 us; speedup 1.0000x reference)
//
#include <hip/hip_runtime.h>
#include <cstdint>
#include <cstddef>

#define DEVINL __device__ __forceinline__

typedef __bf16 bf16x8 __attribute__((ext_vector_type(8)));
typedef float f32x4 __attribute__((ext_vector_type(4)));

static constexpr int NN = 10000;     // nodes
static constexpr int NE = 80000;     // edges
static constexpr int IN_DIM = 1024;
static constexpr int HID = 4096;
static constexpr int OUTD = 256;
static constexpr int M_PAD = 10112;  // 79*128 (also 316*32)

// fp32 -> bf16 round-nearest-even
DEVINL unsigned short f2bf(float f) {
  unsigned int u = __builtin_bit_cast(unsigned int, f);
  u += 0x7fffu + ((u >> 16) & 1u);
  return (unsigned short)(u >> 16);
}
DEVINL float bf2f(unsigned short h) {
  unsigned int u = ((unsigned int)h) << 16;
  return __builtin_bit_cast(float, u);
}

// async global->LDS, 16B per lane; LDS dest is wave-uniform base + lane*16
DEVINL void ld_lds16(const void* g, void* l) {
  __builtin_amdgcn_global_load_lds(
      (const __attribute__((address_space(1))) unsigned int*)g,
      (__attribute__((address_space(3))) unsigned int*)l, 16, 0, 0);
}

// ---------------- fused prep: conv_w1 + conv_w2 + x->bf16 + degree count ----------------
static constexpr int PREP_B1 = 8192;
static constexpr int PREP_B2 = PREP_B1 + 2048;
static constexpr int PREP_B3 = PREP_B2 + 10000;
static constexpr int PREP_NB = PREP_B3 + 313;

__global__ __launch_bounds__(256) void prep_kernel(
    const float* __restrict__ W1l, const float* __restrict__ W1r,
    const float* __restrict__ W2l, const float* __restrict__ W2r,
    const float* __restrict__ x, const int* __restrict__ dst,
    unsigned short* __restrict__ w1cat, unsigned short* __restrict__ w2cat,
    unsigned short* __restrict__ x_bf, int* __restrict__ deg) {
  int b = blockIdx.x;
  int t = threadIdx.x;
  if (b < PREP_B1) {  // w1cat [4096][2048]: row n = [W1_l row n | W1_r row n]
    int g = b * 256 + t;
    int n = g >> 9;
    int kg = g & 511;
    const float* s = (kg < 256) ? (W1l + (size_t)n * 1024 + kg * 4)
                                : (W1r + (size_t)n * 1024 + (kg - 256) * 4);
    float4 v = *(const float4*)s;
    ushort4 p = {f2bf(v.x), f2bf(v.y), f2bf(v.z), f2bf(v.w)};
    ((ushort4*)w1cat)[g] = p;
  } else if (b < PREP_B2) {  // w2cat [512][4096]: rows 0..255 = W2_l, 256..511 = W2_r
    int g = (b - PREP_B1) * 256 + t;
    int n = g >> 10;
    int kg = g & 1023;
    const float* s = (n < 256) ? (W2l + (size_t)n * 4096 + kg * 4)
                               : (W2r + (size_t)(n - 256) * 4096 + kg * 4);
    float4 v = *(const float4*)s;
    ushort4 p = {f2bf(v.x), f2bf(v.y), f2bf(v.z), f2bf(v.w)};
    ((ushort4*)w2cat)[g] = p;
  } else if (b < PREP_B3) {  // x -> bf16, [10000][1024]
    int g = (b - PREP_B2) * 256 + t;
    int i = g >> 8;
    int kg = g & 255;
    float4 v = ((const float4*)(x + (size_t)i * IN_DIM))[kg];
    ushort4 p = {f2bf(v.x), f2bf(v.y), f2bf(v.z), f2bf(v.w)};
    ((ushort4*)(x_bf + (size_t)i * IN_DIM))[kg] = p;
  } else {  // degree count
    int e = (b - PREP_B3) * 256 + t;
    if (e < NE) atomicAdd(&deg[dst[e]], 1);
  }
}

// one-block exclusive scan over NN degrees -> offs[0..NN] and cursor copy cur[]
__global__ __launch_bounds__(256) void scan_kernel(const int* __restrict__ deg,
                                                   int* __restrict__ offs,
                                                   int* __restrict__ cur) {
  __shared__ int part[256];
  constexpr int NPT = 40;  // 256*40 = 10240 >= NN
  int t = threadIdx.x;
  int base = t * NPT;
  int s = 0;
  for (int j = 0; j < NPT; ++j) {
    int n = base + j;
    s += (n < NN) ? deg[n] : 0;
  }
  part[t] = s;
  __syncthreads();
  for (int o = 1; o < 256; o <<= 1) {  // Hillis-Steele inclusive scan
    int v = (t >= o) ? part[t - o] : 0;
    __syncthreads();
    part[t] += v;
    __syncthreads();
  }
  int pre = (t > 0) ? part[t - 1] : 0;
  for (int j = 0; j < NPT; ++j) {
    int n = base + j;
    if (n < NN) {
      offs[n] = pre;
      cur[n] = pre;
      pre += deg[n];
    }
  }
  if (t == 255) offs[NN] = part[255];  // == NE
}

// bin edges: csr[cur[dst]++] = src  (cur pre-seeded with offs by scan)
__global__ void bin_kernel(const int* __restrict__ src, const int* __restrict__ dst,
                           int* __restrict__ cur, int* __restrict__ csr) {
  int e = blockIdx.x * 256 + threadIdx.x;
  if (e < NE) {
    int p = atomicAdd(&cur[dst[e]], 1);
    csr[p] = src[e];
  }
}

// ---------------- layer-1 gather (bf16 source): A1 = [mean_agg(x) | x] ----------------
// grid = M_PAD blocks; rows >= NN are zero pad (absorbs the pad memset).
__global__ __launch_bounds__(256) void gather1_kernel(const unsigned short* __restrict__ x_bf,
                                                      const int* __restrict__ offs,
                                                      const int* __restrict__ csr,
                                                      unsigned short* __restrict__ A1) {
  int i = blockIdx.x;
  int t = threadIdx.x;  // 256 threads x ushort4 = 1024 bf16 = one row
  unsigned short* row = A1 + (size_t)i * 2048;
  if (i >= NN) {
    ushort4 z = {0, 0, 0, 0};
    ((ushort4*)row)[t] = z;
    ((ushort4*)(row + 1024))[t] = z;
    return;
  }
  int beg = offs[i], end = offs[i + 1];
  float4 a0 = {0.f, 0.f, 0.f, 0.f}, a1 = {0.f, 0.f, 0.f, 0.f};
  int j = beg;
  for (; j + 2 <= end; j += 2) {
    int s0 = __builtin_amdgcn_readfirstlane(csr[j]);
    int s1 = __builtin_amdgcn_readfirstlane(csr[j + 1]);
    ushort4 u0 = ((const ushort4*)(x_bf + (size_t)s0 * IN_DIM))[t];
    ushort4 u1 = ((const ushort4*)(x_bf + (size_t)s1 * IN_DIM))[t];
    a0.x += bf2f(u0.x); a0.y += bf2f(u0.y); a0.z += bf2f(u0.z); a0.w += bf2f(u0.w);
    a1.x += bf2f(u1.x); a1.y += bf2f(u1.y); a1.z += bf2f(u1.z); a1.w += bf2f(u1.w);
  }
  if (j < end) {
    int s0 = __builtin_amdgcn_readfirstlane(csr[j]);
    ushort4 u0 = ((const ushort4*)(x_bf + (size_t)s0 * IN_DIM))[t];
    a0.x += bf2f(u0.x); a0.y += bf2f(u0.y); a0.z += bf2f(u0.z); a0.w += bf2f(u0.w);
  }
  float inv = 1.0f / (float)max(end - beg, 1);
  ushort4 ub = ((const ushort4*)(x_bf + (size_t)i * IN_DIM))[t];
  ushort4 pa = {f2bf((a0.x + a1.x) * inv), f2bf((a0.y + a1.y) * inv),
                f2bf((a0.z + a1.z) * inv), f2bf((a0.w + a1.w) * inv)};
  ((ushort4*)row)[t] = pa;           // cols 0..1023  = mean
  ((ushort4*)(row + 1024))[t] = ub;  // cols 1024..2047 = x
}

// ---------------- bf16 MFMA GEMM, templated BK, BM; two block-mapping modes ----------------
// C[M_PAD,N] = A[M_PAD,K] * Bt[N,K]^T. BN=128 fixed; BM in {32,64,128}; 4 waves 2x2.
// Mapping: XBAND=true -> XCD-banded (assumes round-robin pid->XCD: xcd=pid&7 owns
// NUMN/8 n-tiles; B-band ~2MB stays L2-resident per XCD; m-major sweep). Requires
// NUMN%8==0 and grid==NUMM*NUMN. XBAND=false -> Triton-style GM-grouped swizzle.
// LDS chunk swizzle: physical 16B chunk p of row r holds logical chunk p ^ (r&7);
// ds_read_b128 at p=(kk*4+quad)^(l16&7) -> 2-way bank aliasing (free, measured 0 conflicts).
// EPI 1: C0 = bf16 [M][N], relu(acc + bias)   (layer 1)
// EPI 2: split: n<256 -> C0 bf16 [M][256] (p_l), n>=256 -> C1 f32 [M][256] (p_r)
template <int BM, int BK, int K, int N, int NUMM, int NUMN, int GM, int EPI, bool XBAND>
__global__ __launch_bounds__(256) void gemm_kernel(const unsigned short* __restrict__ A,
                                                   const unsigned short* __restrict__ Bt,
                                                   const float* __restrict__ bias,
                                                   void* __restrict__ C0out,
                                                   void* __restrict__ C1out) {
  constexpr int BN = 128;
  constexpr int MI = BM / 32;             // 16-row tiles per wave (m)
  constexpr int NI = 4;                   // 16-col tiles per wave (n)
  constexpr int CPR = BK / 8;             // 16B chunks per LDS row
  constexpr int SA = BM * CPR / 256;      // staging rounds for A (256 thr x 16B)
  constexpr int SB = BN * CPR / 256;
  constexpr int KK = BK / 32;             // MFMA k-steps per tile
  __shared__ unsigned short Asm[BM * BK];
  __shared__ unsigned short Bsm[BN * BK];

  const int pid = blockIdx.x;
  int pm, pn;
  if (XBAND) {
    const int xcd = pid & 7;
    const int slot = pid >> 3;   // 0 .. NUMM*NUMN/8-1
    pm = slot % NUMM;            // m-major within band
    pn = xcd * (NUMN / 8) + slot / NUMM;
  } else {
    constexpr int NPG = GM * NUMN;
    const int gid = pid / NPG;
    const int first_m = gid * GM;
    const int sz = (NUMM - first_m < GM) ? (NUMM - first_m) : GM;
    const int local = pid % NPG;
    pm = first_m + local % sz;
    pn = local / sz;
  }

  const int tid = threadIdx.x;
  const int lane = tid & 63;
  const int wave = tid >> 6;
  const int quad = lane >> 4;
  const int l16 = lane & 15;
  const int wm = (wave & 1) * (BM / 2);
  const int wn = (wave >> 1) * 64;
  const long tm0 = (long)pm * BM;
  const long tn0 = (long)pn * BN;

  f32x4 acc[MI][NI];
#pragma unroll
  for (int i = 0; i < MI; ++i)
#pragma unroll
    for (int j = 0; j < NI; ++j) acc[i][j] = (f32x4){0.f, 0.f, 0.f, 0.f};

  // staging: chunk c = s*256 + tid; row r = c / CPR; physical slot = c % CPR;
  // source logical chunk g = slot ^ (r & 7)  -> global col g*8
  const unsigned short* aSrc[SA];
  unsigned short* aDst[SA];
  const unsigned short* bSrc[SB];
  unsigned short* bDst[SB];
#pragma unroll
  for (int s = 0; s < SA; ++s) {
    int c = s * 256 + wave * 64 + lane;
    int r = c / CPR;
    int g = (c % CPR) ^ (r & 7);
    aSrc[s] = A + (size_t)(tm0 + r) * K + g * 8;
    aDst[s] = Asm + s * 2048 + wave * 512;  // wave-uniform base
  }
#pragma unroll
  for (int s = 0; s < SB; ++s) {
    int c = s * 256 + wave * 64 + lane;
    int r = c / CPR;
    int g = (c % CPR) ^ (r & 7);
    bSrc[s] = Bt + (size_t)(tn0 + r) * K + g * 8;
    bDst[s] = Bsm + s * 2048 + wave * 512;
  }

  const int l7 = l16 & 7;

  for (int k0 = 0; k0 < K; k0 += BK) {
#pragma unroll
    for (int s = 0; s < SA; ++s) ld_lds16(aSrc[s] + k0, aDst[s]);
#pragma unroll
    for (int s = 0; s < SB; ++s) ld_lds16(bSrc[s] + k0, bDst[s]);
    __syncthreads();  // drains vmcnt -> LDS tiles complete

#pragma unroll
    for (int kk = 0; kk < KK; ++kk) {
      const int p = (kk * 4 + quad) ^ l7;  // physical chunk for this frag
      bf16x8 af[MI], bv[NI];
#pragma unroll
      for (int i = 0; i < MI; ++i) {
        int ra = wm + i * 16 + l16;
        af[i] = *(const bf16x8*)(Asm + ra * BK + p * 8);
      }
#pragma unroll
      for (int j = 0; j < NI; ++j) {
        int rb = wn + j * 16 + l16;
        bv[j] = *(const bf16x8*)(Bsm + rb * BK + p * 8);
      }
#pragma unroll
      for (int i = 0; i < MI; ++i)
#pragma unroll
        for (int j = 0; j < NI; ++j)
          acc[i][j] = __builtin_amdgcn_mfma_f32_16x16x32_bf16(af[i], bv[j], acc[i][j], 0, 0, 0);
    }
    __syncthreads();  // LDS reads done before next stage overwrites
  }

  // epilogue: C/D layout col = lane&15, row = quad*4 + reg
  if (EPI == 1) {
    unsigned short* C = (unsigned short*)C0out;
#pragma unroll
    for (int i = 0; i < MI; ++i) {
      long m0 = tm0 + wm + i * 16 + quad * 4;
#pragma unroll
      for (int j = 0; j < NI; ++j) {
        int n = (int)tn0 + wn + j * 16 + l16;
        float bvs = bias[n];
#pragma unroll
        for (int r = 0; r < 4; ++r) {
          float v = acc[i][j][r] + bvs;
          v = fmaxf(v, 0.0f);
          C[(size_t)(m0 + r) * N + n] = f2bf(v);
        }
      }
    }
  } else {  // EPI == 2: split p_l (bf16) / p_r (f32), both stride 256
    unsigned short* PL = (unsigned short*)C0out;
    float* PR = (float*)C1out;
#pragma unroll
    for (int i = 0; i < MI; ++i) {
      long m0 = tm0 + wm + i * 16 + quad * 4;
#pragma unroll
      for (int j = 0; j < NI; ++j) {
        int n = (int)tn0 + wn + j * 16 + l16;  // 16-aligned per (j): branch is uniform
        if (n < 256) {
#pragma unroll
          for (int r = 0; r < 4; ++r) PL[(size_t)(m0 + r) * 256 + n] = f2bf(acc[i][j][r]);
        } else {
#pragma unroll
          for (int r = 0; r < 4; ++r) PR[(size_t)(m0 + r) * 256 + (n - 256)] = acc[i][j][r];
        }
      }
    }
  }
}

// ---------------- layer-2 gather + bias + p_r + log_softmax (fused) ----------------
// 128 threads/block, thread t owns cols {2t, 2t+1}; p_l read as packed 2xbf16; edge loop x2.
__global__ __launch_bounds__(128) void gather2_final_kernel(const unsigned short* __restrict__ pl,
                                                            const float* __restrict__ pr,
                                                            const int* __restrict__ offs,
                                                            const int* __restrict__ csr,
                                                            const float* __restrict__ b2,
                                                            float* __restrict__ out) {
  int i = blockIdx.x;
  int t = threadIdx.x;  // 0..127
  int beg = offs[i], end = offs[i + 1];
  float a0 = 0.f, a1 = 0.f, c0 = 0.f, c1 = 0.f;
  int j = beg;
  for (; j + 2 <= end; j += 2) {
    int s0 = __builtin_amdgcn_readfirstlane(csr[j]);
    int s1 = __builtin_amdgcn_readfirstlane(csr[j + 1]);
    unsigned int u0 = ((const unsigned int*)(pl + (size_t)s0 * 256))[t];
    unsigned int u1 = ((const unsigned int*)(pl + (size_t)s1 * 256))[t];
    a0 += bf2f((unsigned short)(u0 & 0xffffu));
    a1 += bf2f((unsigned short)(u0 >> 16));
    c0 += bf2f((unsigned short)(u1 & 0xffffu));
    c1 += bf2f((unsigned short)(u1 >> 16));
  }
  if (j < end) {
    int s0 = __builtin_amdgcn_readfirstlane(csr[j]);
    unsigned int u0 = ((const unsigned int*)(pl + (size_t)s0 * 256))[t];
    a0 += bf2f((unsigned short)(u0 & 0xffffu));
    a1 += bf2f((unsigned short)(u0 >> 16));
  }
  float inv = 1.0f / (float)max(end - beg, 1);
  float2 bv = ((const float2*)b2)[t];
  float2 pv = ((const float2*)(pr + (size_t)i * 256))[t];
  float v0 = (a0 + c0) * inv + bv.x + pv.x;
  float v1 = (a1 + c1) * inv + bv.y + pv.y;

  __shared__ float sm[2], ss[2];
  int w = t >> 6;
  float m = fmaxf(v0, v1);
#pragma unroll
  for (int o = 32; o > 0; o >>= 1) m = fmaxf(m, __shfl_xor(m, o, 64));
  if ((t & 63) == 0) sm[w] = m;
  __syncthreads();
  m = fmaxf(sm[0], sm[1]);

  float s = __expf(v0 - m) + __expf(v1 - m);
#pragma unroll
  for (int o = 32; o > 0; o >>= 1) s += __shfl_xor(s, o, 64);
  if ((t & 63) == 0) ss[w] = s;
  __syncthreads();
  float ls = logf(ss[0] + ss[1]);

  float2 o2 = {v0 - m - ls, v1 - m - ls};
  ((float2*)(out + (size_t)i * OUTD))[t] = o2;
}

// ---------------- workspace layout (bytes) ----------------
static constexpr size_t OFF_A1 = 0;
static constexpr size_t OFF_W1 = OFF_A1 + (size_t)M_PAD * 2048 * 2;
static constexpr size_t OFF_HB = OFF_W1 + (size_t)HID * 2048 * 2;
static constexpr size_t OFF_W2 = OFF_HB + (size_t)M_PAD * HID * 2;
static constexpr size_t OFF_XBF = OFF_W2 - (size_t)NN * IN_DIM * 2;  // tail of h_b
static constexpr size_t OFF_DEG = OFF_W2 + (size_t)512 * HID * 2;
static constexpr size_t OFF_OFFS = OFF_DEG + (size_t)NN * 4;
static constexpr size_t OFF_CUR = OFF_OFFS + (size_t)(NN + 4) * 4;
static constexpr size_t OFF_CSR = OFF_CUR + (size_t)NN * 4;
static constexpr size_t OFF_PL = OFF_A1;                              // alias: A1 dead after gemm1
static constexpr size_t OFF_PR = OFF_PL + (size_t)M_PAD * 256 * 2;

extern "C" void kernel_launch(void* const* d_in, const int* in_sizes, int n_in,
                              void* d_out, int out_size, void* d_ws, size_t ws_size,
                              hipStream_t stream) {
  const float* x = (const float*)d_in[0];
  const int* ei = (const int*)d_in[1];
  const int* src = ei;
  const int* dst = ei + NE;
  const float* W1_l = (const float*)d_in[2];
  const float* b1_l = (const float*)d_in[3];
  const float* W1_r = (const float*)d_in[4];
  const float* W2_l = (const float*)d_in[5];
  const float* b2_l = (const float*)d_in[6];
  const float* W2_r = (const float*)d_in[7];
  float* out = (float*)d_out;

  char* ws = (char*)d_ws;
  unsigned short* A1 = (unsigned short*)(ws + OFF_A1);
  unsigned short* w1cat = (unsigned short*)(ws + OFF_W1);
  unsigned short* h_b = (unsigned short*)(ws + OFF_HB);
  unsigned short* x_bf = (unsigned short*)(ws + OFF_XBF);
  unsigned short* w2cat = (unsigned short*)(ws + OFF_W2);
  int* deg = (int*)(ws + OFF_DEG);
  int* offs = (int*)(ws + OFF_OFFS);
  int* cur = (int*)(ws + OFF_CUR);
  int* csr = (int*)(ws + OFF_CSR);
  unsigned short* pl = (unsigned short*)(ws + OFF_PL);
  float* pr = (float*)(ws + OFF_PR);

  // zero degree counters (ws is poisoned 0xAA before every call)
  hipMemsetAsync(deg, 0, (size_t)NN * 4, stream);

  // fused prep: weight converts + x->bf16 + degree count
  prep_kernel<<<PREP_NB, 256, 0, stream>>>(W1_l, W1_r, W2_l, W2_r, x, dst,
                                           w1cat, w2cat, x_bf, deg);
  scan_kernel<<<1, 256, 0, stream>>>(deg, offs, cur);
  bin_kernel<<<(NE + 255) / 256, 256, 0, stream>>>(src, dst, cur, csr);

  // A1 = [mean | x] bf16 via CSR gather (no atomics); rows >= NN zeroed here
  gather1_kernel<<<M_PAD, 256, 0, stream>>>(x_bf, offs, csr, A1);

  // h = relu(A1 @ w1cat^T + b1)  -> bf16 [10112][4096]; BK=64, XCD-banded mapping
  gemm_kernel<128, 64, 2048, 4096, 79, 32, 32, 1, true>
      <<<79 * 32, 256, 0, stream>>>(A1, w1cat, b1_l, h_b, nullptr);
  // [p_l | p_r] = h @ w2cat^T -> p_l bf16 [10112][256], p_r f32 [10112][256]
  // BM=32 -> 1264 blocks (~5/CU) for cross-block barrier overlap; GM-grouped
  gemm_kernel<32, 128, 4096, 512, 316, 4, 64, 2, false>
      <<<316 * 4, 256, 0, stream>>>(h_b, w2cat, nullptr, pl, pr);

  // mean of p_l over in-edges + bias + p_r, then log_softmax
  gather2_final_kernel<<<NN, 128, 0, stream>>>(pl, pr, offs, csr, b2_l, out);
}

// Round 8
// 444.264 us; speedup vs baseline: 1.0897x; 1.0897x over previous
//
#include <hip/hip_runtime.h>
#include <cstdint>
#include <cstddef>

#define DEVINL __device__ __forceinline__

typedef __bf16 bf16x8 __attribute__((ext_vector_type(8)));
typedef float f32x4 __attribute__((ext_vector_type(4)));

static constexpr int NN = 10000;     // nodes
static constexpr int NE = 80000;     // edges
static constexpr int IN_DIM = 1024;
static constexpr int HID = 4096;
static constexpr int OUTD = 256;
static constexpr int M_PAD = 10112;  // 79*128 (also 158*64)

// fp32 -> bf16 round-nearest-even
DEVINL unsigned short f2bf(float f) {
  unsigned int u = __builtin_bit_cast(unsigned int, f);
  u += 0x7fffu + ((u >> 16) & 1u);
  return (unsigned short)(u >> 16);
}
DEVINL float bf2f(unsigned short h) {
  unsigned int u = ((unsigned int)h) << 16;
  return __builtin_bit_cast(float, u);
}

// async global->LDS, 16B per lane; LDS dest is wave-uniform base + lane*16
DEVINL void ld_lds16(const void* g, void* l) {
  __builtin_amdgcn_global_load_lds(
      (const __attribute__((address_space(1))) unsigned int*)g,
      (__attribute__((address_space(3))) unsigned int*)l, 16, 0, 0);
}

// ---------------- fused prep: conv_w1 + conv_w2 + x->bf16 + degree count ----------------
static constexpr int PREP_B1 = 8192;
static constexpr int PREP_B2 = PREP_B1 + 2048;
static constexpr int PREP_B3 = PREP_B2 + 10000;
static constexpr int PREP_NB = PREP_B3 + 313;

__global__ __launch_bounds__(256) void prep_kernel(
    const float* __restrict__ W1l, const float* __restrict__ W1r,
    const float* __restrict__ W2l, const float* __restrict__ W2r,
    const float* __restrict__ x, const int* __restrict__ dst,
    unsigned short* __restrict__ w1cat, unsigned short* __restrict__ w2cat,
    unsigned short* __restrict__ x_bf, int* __restrict__ deg) {
  int b = blockIdx.x;
  int t = threadIdx.x;
  if (b < PREP_B1) {  // w1cat [4096][2048]: row n = [W1_l row n | W1_r row n]
    int g = b * 256 + t;
    int n = g >> 9;
    int kg = g & 511;
    const float* s = (kg < 256) ? (W1l + (size_t)n * 1024 + kg * 4)
                                : (W1r + (size_t)n * 1024 + (kg - 256) * 4);
    float4 v = *(const float4*)s;
    ushort4 p = {f2bf(v.x), f2bf(v.y), f2bf(v.z), f2bf(v.w)};
    ((ushort4*)w1cat)[g] = p;
  } else if (b < PREP_B2) {  // w2cat [512][4096]: rows 0..255 = W2_l, 256..511 = W2_r
    int g = (b - PREP_B1) * 256 + t;
    int n = g >> 10;
    int kg = g & 1023;
    const float* s = (n < 256) ? (W2l + (size_t)n * 4096 + kg * 4)
                               : (W2r + (size_t)(n - 256) * 4096 + kg * 4);
    float4 v = *(const float4*)s;
    ushort4 p = {f2bf(v.x), f2bf(v.y), f2bf(v.z), f2bf(v.w)};
    ((ushort4*)w2cat)[g] = p;
  } else if (b < PREP_B3) {  // x -> bf16, [10000][1024]
    int g = (b - PREP_B2) * 256 + t;
    int i = g >> 8;
    int kg = g & 255;
    float4 v = ((const float4*)(x + (size_t)i * IN_DIM))[kg];
    ushort4 p = {f2bf(v.x), f2bf(v.y), f2bf(v.z), f2bf(v.w)};
    ((ushort4*)(x_bf + (size_t)i * IN_DIM))[kg] = p;
  } else {  // degree count
    int e = (b - PREP_B3) * 256 + t;
    if (e < NE) atomicAdd(&deg[dst[e]], 1);
  }
}

// one-block exclusive scan over NN degrees -> offs[0..NN] and cursor copy cur[]
__global__ __launch_bounds__(256) void scan_kernel(const int* __restrict__ deg,
                                                   int* __restrict__ offs,
                                                   int* __restrict__ cur) {
  __shared__ int part[256];
  constexpr int NPT = 40;  // 256*40 = 10240 >= NN
  int t = threadIdx.x;
  int base = t * NPT;
  int s = 0;
  for (int j = 0; j < NPT; ++j) {
    int n = base + j;
    s += (n < NN) ? deg[n] : 0;
  }
  part[t] = s;
  __syncthreads();
  for (int o = 1; o < 256; o <<= 1) {  // Hillis-Steele inclusive scan
    int v = (t >= o) ? part[t - o] : 0;
    __syncthreads();
    part[t] += v;
    __syncthreads();
  }
  int pre = (t > 0) ? part[t - 1] : 0;
  for (int j = 0; j < NPT; ++j) {
    int n = base + j;
    if (n < NN) {
      offs[n] = pre;
      cur[n] = pre;
      pre += deg[n];
    }
  }
  if (t == 255) offs[NN] = part[255];  // == NE
}

// bin edges: csr[cur[dst]++] = src  (cur pre-seeded with offs by scan)
__global__ void bin_kernel(const int* __restrict__ src, const int* __restrict__ dst,
                           int* __restrict__ cur, int* __restrict__ csr) {
  int e = blockIdx.x * 256 + threadIdx.x;
  if (e < NE) {
    int p = atomicAdd(&cur[dst[e]], 1);
    csr[p] = src[e];
  }
}

// ---------------- layer-1 gather (bf16 source): A1 = [mean_agg(x) | x] ----------------
// grid = M_PAD blocks; rows >= NN are zero pad (absorbs the pad memset).
__global__ __launch_bounds__(256) void gather1_kernel(const unsigned short* __restrict__ x_bf,
                                                      const int* __restrict__ offs,
                                                      const int* __restrict__ csr,
                                                      unsigned short* __restrict__ A1) {
  int i = blockIdx.x;
  int t = threadIdx.x;  // 256 threads x ushort4 = 1024 bf16 = one row
  unsigned short* row = A1 + (size_t)i * 2048;
  if (i >= NN) {
    ushort4 z = {0, 0, 0, 0};
    ((ushort4*)row)[t] = z;
    ((ushort4*)(row + 1024))[t] = z;
    return;
  }
  int beg = offs[i], end = offs[i + 1];
  float4 a0 = {0.f, 0.f, 0.f, 0.f}, a1 = {0.f, 0.f, 0.f, 0.f};
  int j = beg;
  for (; j + 2 <= end; j += 2) {
    int s0 = __builtin_amdgcn_readfirstlane(csr[j]);
    int s1 = __builtin_amdgcn_readfirstlane(csr[j + 1]);
    ushort4 u0 = ((const ushort4*)(x_bf + (size_t)s0 * IN_DIM))[t];
    ushort4 u1 = ((const ushort4*)(x_bf + (size_t)s1 * IN_DIM))[t];
    a0.x += bf2f(u0.x); a0.y += bf2f(u0.y); a0.z += bf2f(u0.z); a0.w += bf2f(u0.w);
    a1.x += bf2f(u1.x); a1.y += bf2f(u1.y); a1.z += bf2f(u1.z); a1.w += bf2f(u1.w);
  }
  if (j < end) {
    int s0 = __builtin_amdgcn_readfirstlane(csr[j]);
    ushort4 u0 = ((const ushort4*)(x_bf + (size_t)s0 * IN_DIM))[t];
    a0.x += bf2f(u0.x); a0.y += bf2f(u0.y); a0.z += bf2f(u0.z); a0.w += bf2f(u0.w);
  }
  float inv = 1.0f / (float)max(end - beg, 1);
  ushort4 ub = ((const ushort4*)(x_bf + (size_t)i * IN_DIM))[t];
  ushort4 pa = {f2bf((a0.x + a1.x) * inv), f2bf((a0.y + a1.y) * inv),
                f2bf((a0.z + a1.z) * inv), f2bf((a0.w + a1.w) * inv)};
  ((ushort4*)row)[t] = pa;           // cols 0..1023  = mean
  ((ushort4*)(row + 1024))[t] = ub;  // cols 1024..2047 = x
}

// ---------------- bf16 MFMA GEMM, templated BK / split-K ----------------
// C[M_PAD,N] = A[M_PAD,K] * Bt[N,K]^T. BN=128 fixed; BM in {64,128}; 4 waves 2x2.
// Block mapping: Triton-style GM-grouped swizzle (R5 config — near the per-XCD-L2
// traffic bound; XCD-banded m-major sweep measured 2.5x FETCH regression, do not revisit).
// Split-K: KSPLIT launches in grid.y, each covers K/KSPLIT; EPI 3 writes bf16 partial.
// LDS chunk swizzle: physical 16B chunk p of row r holds logical chunk p ^ (r&7);
// ds_read_b128 at p=(kk*4+quad)^(l16&7) -> 2-way bank aliasing (free, measured 0 conflicts).
// EPI 1: C0 = bf16 [M][N], relu(acc + bias)             (layer 1)
// EPI 3: C0 = bf16 partial [KSPLIT][M][N] at grid.y     (layer 2, reduced later)
template <int BM, int BK, int K, int KSPLIT, int N, int NUMM, int NUMN, int GM, int EPI>
__global__ __launch_bounds__(256) void gemm_kernel(const unsigned short* __restrict__ A,
                                                   const unsigned short* __restrict__ Bt,
                                                   const float* __restrict__ bias,
                                                   void* __restrict__ C0out) {
  constexpr int BN = 128;
  constexpr int MI = BM / 32;             // 16-row tiles per wave (m)
  constexpr int NI = 4;                   // 16-col tiles per wave (n)
  constexpr int CPR = BK / 8;             // 16B chunks per LDS row
  constexpr int SA = BM * CPR / 256;      // staging rounds for A (256 thr x 16B)
  constexpr int SB = BN * CPR / 256;
  constexpr int KK = BK / 32;             // MFMA k-steps per tile
  constexpr int KS = K / KSPLIT;          // K range per split
  __shared__ unsigned short Asm[BM * BK];
  __shared__ unsigned short Bsm[BN * BK];

  // grouped swizzle on grid.x
  constexpr int NPG = GM * NUMN;
  const int pid = blockIdx.x;
  const int gid = pid / NPG;
  const int first_m = gid * GM;
  const int sz = (NUMM - first_m < GM) ? (NUMM - first_m) : GM;
  const int local = pid % NPG;
  const int pm = first_m + local % sz;
  const int pn = local / sz;
  const int koff = (KSPLIT > 1) ? (int)blockIdx.y * KS : 0;

  const int tid = threadIdx.x;
  const int lane = tid & 63;
  const int wave = tid >> 6;
  const int quad = lane >> 4;
  const int l16 = lane & 15;
  const int wm = (wave & 1) * (BM / 2);
  const int wn = (wave >> 1) * 64;
  const long tm0 = (long)pm * BM;
  const long tn0 = (long)pn * BN;

  f32x4 acc[MI][NI];
#pragma unroll
  for (int i = 0; i < MI; ++i)
#pragma unroll
    for (int j = 0; j < NI; ++j) acc[i][j] = (f32x4){0.f, 0.f, 0.f, 0.f};

  // staging: chunk c = s*256 + tid; row r = c / CPR; physical slot = c % CPR;
  // source logical chunk g = slot ^ (r & 7)  -> global col g*8
  const unsigned short* aSrc[SA];
  unsigned short* aDst[SA];
  const unsigned short* bSrc[SB];
  unsigned short* bDst[SB];
#pragma unroll
  for (int s = 0; s < SA; ++s) {
    int c = s * 256 + wave * 64 + lane;
    int r = c / CPR;
    int g = (c % CPR) ^ (r & 7);
    aSrc[s] = A + (size_t)(tm0 + r) * K + koff + g * 8;
    aDst[s] = Asm + s * 2048 + wave * 512;  // wave-uniform base
  }
#pragma unroll
  for (int s = 0; s < SB; ++s) {
    int c = s * 256 + wave * 64 + lane;
    int r = c / CPR;
    int g = (c % CPR) ^ (r & 7);
    bSrc[s] = Bt + (size_t)(tn0 + r) * K + koff + g * 8;
    bDst[s] = Bsm + s * 2048 + wave * 512;
  }

  const int l7 = l16 & 7;

  for (int k0 = 0; k0 < KS; k0 += BK) {
#pragma unroll
    for (int s = 0; s < SA; ++s) ld_lds16(aSrc[s] + k0, aDst[s]);
#pragma unroll
    for (int s = 0; s < SB; ++s) ld_lds16(bSrc[s] + k0, bDst[s]);
    __syncthreads();  // drains vmcnt -> LDS tiles complete

#pragma unroll
    for (int kk = 0; kk < KK; ++kk) {
      const int p = (kk * 4 + quad) ^ l7;  // physical chunk for this frag
      bf16x8 af[MI], bv[NI];
#pragma unroll
      for (int i = 0; i < MI; ++i) {
        int ra = wm + i * 16 + l16;
        af[i] = *(const bf16x8*)(Asm + ra * BK + p * 8);
      }
#pragma unroll
      for (int j = 0; j < NI; ++j) {
        int rb = wn + j * 16 + l16;
        bv[j] = *(const bf16x8*)(Bsm + rb * BK + p * 8);
      }
#pragma unroll
      for (int i = 0; i < MI; ++i)
#pragma unroll
        for (int j = 0; j < NI; ++j)
          acc[i][j] = __builtin_amdgcn_mfma_f32_16x16x32_bf16(af[i], bv[j], acc[i][j], 0, 0, 0);
    }
    __syncthreads();  // LDS reads done before next stage overwrites
  }

  // epilogue: C/D layout col = lane&15, row = quad*4 + reg
  if (EPI == 1) {
    unsigned short* C = (unsigned short*)C0out;
#pragma unroll
    for (int i = 0; i < MI; ++i) {
      long m0 = tm0 + wm + i * 16 + quad * 4;
#pragma unroll
      for (int j = 0; j < NI; ++j) {
        int n = (int)tn0 + wn + j * 16 + l16;
        float bvs = bias[n];
#pragma unroll
        for (int r = 0; r < 4; ++r) {
          float v = acc[i][j][r] + bvs;
          v = fmaxf(v, 0.0f);
          C[(size_t)(m0 + r) * N + n] = f2bf(v);
        }
      }
    }
  } else {  // EPI == 3: bf16 partial, slab per grid.y
    unsigned short* C = (unsigned short*)C0out + (size_t)blockIdx.y * NUMM * BM * N;
#pragma unroll
    for (int i = 0; i < MI; ++i) {
      long m0 = tm0 + wm + i * 16 + quad * 4;
#pragma unroll
      for (int j = 0; j < NI; ++j) {
        int n = (int)tn0 + wn + j * 16 + l16;
#pragma unroll
        for (int r = 0; r < 4; ++r) C[(size_t)(m0 + r) * N + n] = f2bf(acc[i][j][r]);
      }
    }
  }
}

// ---------------- split-K reduce: pl/pr = P0 + P1 ----------------
// P = [2][M_PAD][512] bf16. grid = M_PAD/4 blocks, 256 threads; thread handles 8 cols
// of one row: row = blk*4 + tid/64, col = (tid&63)*8. cols<256 -> pl bf16; else pr f32.
__global__ __launch_bounds__(256) void reduce2_kernel(const unsigned short* __restrict__ P,
                                                      unsigned short* __restrict__ pl,
                                                      float* __restrict__ pr) {
  int tid = threadIdx.x;
  size_t row = (size_t)blockIdx.x * 4 + (tid >> 6);
  int col = (tid & 63) * 8;
  size_t base = row * 512 + col;
  uint4 a = *(const uint4*)(P + base);
  uint4 b = *(const uint4*)(P + (size_t)M_PAD * 512 + base);
  float s[8];
  const unsigned int* aw = (const unsigned int*)&a;
  const unsigned int* bw = (const unsigned int*)&b;
#pragma unroll
  for (int j = 0; j < 4; ++j) {
    s[2 * j] = bf2f((unsigned short)(aw[j] & 0xffffu)) + bf2f((unsigned short)(bw[j] & 0xffffu));
    s[2 * j + 1] = bf2f((unsigned short)(aw[j] >> 16)) + bf2f((unsigned short)(bw[j] >> 16));
  }
  if (col < 256) {
    unsigned int o[4];
#pragma unroll
    for (int j = 0; j < 4; ++j)
      o[j] = (unsigned int)f2bf(s[2 * j]) | ((unsigned int)f2bf(s[2 * j + 1]) << 16);
    *(uint4*)(pl + row * 256 + col) = *(const uint4*)o;
  } else {
    float* d = pr + row * 256 + (col - 256);
    *(float4*)d = (float4){s[0], s[1], s[2], s[3]};
    *(float4*)(d + 4) = (float4){s[4], s[5], s[6], s[7]};
  }
}

// ---------------- layer-2 gather + bias + p_r + log_softmax (fused) ----------------
// 128 threads/block, thread t owns cols {2t, 2t+1}; p_l read as packed 2xbf16; edge loop x2.
__global__ __launch_bounds__(128) void gather2_final_kernel(const unsigned short* __restrict__ pl,
                                                            const float* __restrict__ pr,
                                                            const int* __restrict__ offs,
                                                            const int* __restrict__ csr,
                                                            const float* __restrict__ b2,
                                                            float* __restrict__ out) {
  int i = blockIdx.x;
  int t = threadIdx.x;  // 0..127
  int beg = offs[i], end = offs[i + 1];
  float a0 = 0.f, a1 = 0.f, c0 = 0.f, c1 = 0.f;
  int j = beg;
  for (; j + 2 <= end; j += 2) {
    int s0 = __builtin_amdgcn_readfirstlane(csr[j]);
    int s1 = __builtin_amdgcn_readfirstlane(csr[j + 1]);
    unsigned int u0 = ((const unsigned int*)(pl + (size_t)s0 * 256))[t];
    unsigned int u1 = ((const unsigned int*)(pl + (size_t)s1 * 256))[t];
    a0 += bf2f((unsigned short)(u0 & 0xffffu));
    a1 += bf2f((unsigned short)(u0 >> 16));
    c0 += bf2f((unsigned short)(u1 & 0xffffu));
    c1 += bf2f((unsigned short)(u1 >> 16));
  }
  if (j < end) {
    int s0 = __builtin_amdgcn_readfirstlane(csr[j]);
    unsigned int u0 = ((const unsigned int*)(pl + (size_t)s0 * 256))[t];
    a0 += bf2f((unsigned short)(u0 & 0xffffu));
    a1 += bf2f((unsigned short)(u0 >> 16));
  }
  float inv = 1.0f / (float)max(end - beg, 1);
  float2 bv = ((const float2*)b2)[t];
  float2 pv = ((const float2*)(pr + (size_t)i * 256))[t];
  float v0 = (a0 + c0) * inv + bv.x + pv.x;
  float v1 = (a1 + c1) * inv + bv.y + pv.y;

  __shared__ float sm[2], ss[2];
  int w = t >> 6;
  float m = fmaxf(v0, v1);
#pragma unroll
  for (int o = 32; o > 0; o >>= 1) m = fmaxf(m, __shfl_xor(m, o, 64));
  if ((t & 63) == 0) sm[w] = m;
  __syncthreads();
  m = fmaxf(sm[0], sm[1]);

  float s = __expf(v0 - m) + __expf(v1 - m);
#pragma unroll
  for (int o = 32; o > 0; o >>= 1) s += __shfl_xor(s, o, 64);
  if ((t & 63) == 0) ss[w] = s;
  __syncthreads();
  float ls = logf(ss[0] + ss[1]);

  float2 o2 = {v0 - m - ls, v1 - m - ls};
  ((float2*)(out + (size_t)i * OUTD))[t] = o2;
}

// ---------------- workspace layout (bytes) ----------------
// A1 region [41.4 MB] reused after GEMM1 as: P0/P1 bf16 [2][10112][512] (20.7 MB)
//   + pl bf16 [10112][256] (5.2 MB) + pr f32 [10112][256] (10.35 MB) = 36.3 MB  OK
static constexpr size_t OFF_A1 = 0;
static constexpr size_t OFF_W1 = OFF_A1 + (size_t)M_PAD * 2048 * 2;
static constexpr size_t OFF_HB = OFF_W1 + (size_t)HID * 2048 * 2;
static constexpr size_t OFF_W2 = OFF_HB + (size_t)M_PAD * HID * 2;
static constexpr size_t OFF_XBF = OFF_W2 - (size_t)NN * IN_DIM * 2;  // tail of h_b
static constexpr size_t OFF_DEG = OFF_W2 + (size_t)512 * HID * 2;
static constexpr size_t OFF_OFFS = OFF_DEG + (size_t)NN * 4;
static constexpr size_t OFF_CUR = OFF_OFFS + (size_t)(NN + 4) * 4;
static constexpr size_t OFF_CSR = OFF_CUR + (size_t)NN * 4;
static constexpr size_t OFF_P = OFF_A1;                               // [2][M_PAD][512] bf16
static constexpr size_t OFF_PL = OFF_P + (size_t)2 * M_PAD * 512 * 2;
static constexpr size_t OFF_PR = OFF_PL + (size_t)M_PAD * 256 * 2;

extern "C" void kernel_launch(void* const* d_in, const int* in_sizes, int n_in,
                              void* d_out, int out_size, void* d_ws, size_t ws_size,
                              hipStream_t stream) {
  const float* x = (const float*)d_in[0];
  const int* ei = (const int*)d_in[1];
  const int* src = ei;
  const int* dst = ei + NE;
  const float* W1_l = (const float*)d_in[2];
  const float* b1_l = (const float*)d_in[3];
  const float* W1_r = (const float*)d_in[4];
  const float* W2_l = (const float*)d_in[5];
  const float* b2_l = (const float*)d_in[6];
  const float* W2_r = (const float*)d_in[7];
  float* out = (float*)d_out;

  char* ws = (char*)d_ws;
  unsigned short* A1 = (unsigned short*)(ws + OFF_A1);
  unsigned short* w1cat = (unsigned short*)(ws + OFF_W1);
  unsigned short* h_b = (unsigned short*)(ws + OFF_HB);
  unsigned short* x_bf = (unsigned short*)(ws + OFF_XBF);
  unsigned short* w2cat = (unsigned short*)(ws + OFF_W2);
  int* deg = (int*)(ws + OFF_DEG);
  int* offs = (int*)(ws + OFF_OFFS);
  int* cur = (int*)(ws + OFF_CUR);
  int* csr = (int*)(ws + OFF_CSR);
  unsigned short* P = (unsigned short*)(ws + OFF_P);
  unsigned short* pl = (unsigned short*)(ws + OFF_PL);
  float* pr = (float*)(ws + OFF_PR);

  // zero degree counters (ws is poisoned 0xAA before every call)
  hipMemsetAsync(deg, 0, (size_t)NN * 4, stream);

  // fused prep: weight converts + x->bf16 + degree count
  prep_kernel<<<PREP_NB, 256, 0, stream>>>(W1_l, W1_r, W2_l, W2_r, x, dst,
                                           w1cat, w2cat, x_bf, deg);
  scan_kernel<<<1, 256, 0, stream>>>(deg, offs, cur);
  bin_kernel<<<(NE + 255) / 256, 256, 0, stream>>>(src, dst, cur, csr);

  // A1 = [mean | x] bf16 via CSR gather (no atomics); rows >= NN zeroed here
  gather1_kernel<<<M_PAD, 256, 0, stream>>>(x_bf, offs, csr, A1);

  // h = relu(A1 @ w1cat^T + b1)  -> bf16 [10112][4096]; BK=64, GM=32 grouped (R5 config)
  gemm_kernel<128, 64, 2048, 1, 4096, 79, 32, 32, 1>
      <<<79 * 32, 256, 0, stream>>>(A1, w1cat, b1_l, h_b);
  // split-K=2: P[s] = h[:, s*2048:(s+1)*2048] @ w2cat[:, same]^T -> bf16 [2][10112][512]
  gemm_kernel<64, 128, 4096, 2, 512, 158, 4, 64, 3>
      <<<dim3(158 * 4, 2), 256, 0, stream>>>(h_b, w2cat, nullptr, P);
  // pl/pr = P0 + P1  (pl bf16 [M][256], pr f32 [M][256])
  reduce2_kernel<<<M_PAD / 4, 256, 0, stream>>>(P, pl, pr);

  // mean of p_l over in-edges + bias + p_r, then log_softmax
  gather2_final_kernel<<<NN, 128, 0, stream>>>(pl, pr, offs, csr, b2_l, out);
}

// Round 9
// 441.549 us; speedup vs baseline: 1.0964x; 1.0061x over previous
//
#include <hip/hip_runtime.h>
#include <cstdint>
#include <cstddef>

#define DEVINL __device__ __forceinline__

typedef __bf16 bf16x8 __attribute__((ext_vector_type(8)));
typedef float f32x4 __attribute__((ext_vector_type(4)));

static constexpr int NN = 10000;     // nodes
static constexpr int NE = 80000;     // edges
static constexpr int IN_DIM = 1024;
static constexpr int HID = 4096;
static constexpr int OUTD = 256;
static constexpr int M_PAD = 10112;  // 79*128 (also 158*64)

// fp32 -> bf16 round-nearest-even
DEVINL unsigned short f2bf(float f) {
  unsigned int u = __builtin_bit_cast(unsigned int, f);
  u += 0x7fffu + ((u >> 16) & 1u);
  return (unsigned short)(u >> 16);
}
DEVINL float bf2f(unsigned short h) {
  unsigned int u = ((unsigned int)h) << 16;
  return __builtin_bit_cast(float, u);
}

// async global->LDS, 16B per lane; LDS dest is wave-uniform base + lane*16
DEVINL void ld_lds16(const void* g, void* l) {
  __builtin_amdgcn_global_load_lds(
      (const __attribute__((address_space(1))) unsigned int*)g,
      (__attribute__((address_space(3))) unsigned int*)l, 16, 0, 0);
}

// ---------------- fused prep: conv_w1 + conv_w2 + x->bf16 + degree count ----------------
static constexpr int PREP_B1 = 8192;
static constexpr int PREP_B2 = PREP_B1 + 2048;
static constexpr int PREP_B3 = PREP_B2 + 10000;
static constexpr int PREP_NB = PREP_B3 + 313;

__global__ __launch_bounds__(256) void prep_kernel(
    const float* __restrict__ W1l, const float* __restrict__ W1r,
    const float* __restrict__ W2l, const float* __restrict__ W2r,
    const float* __restrict__ x, const int* __restrict__ dst,
    unsigned short* __restrict__ w1cat, unsigned short* __restrict__ w2cat,
    unsigned short* __restrict__ x_bf, int* __restrict__ deg) {
  int b = blockIdx.x;
  int t = threadIdx.x;
  if (b < PREP_B1) {  // w1cat [4096][2048]: row n = [W1_l row n | W1_r row n]
    int g = b * 256 + t;
    int n = g >> 9;
    int kg = g & 511;
    const float* s = (kg < 256) ? (W1l + (size_t)n * 1024 + kg * 4)
                                : (W1r + (size_t)n * 1024 + (kg - 256) * 4);
    float4 v = *(const float4*)s;
    ushort4 p = {f2bf(v.x), f2bf(v.y), f2bf(v.z), f2bf(v.w)};
    ((ushort4*)w1cat)[g] = p;
  } else if (b < PREP_B2) {  // w2cat [512][4096]: rows 0..255 = W2_l, 256..511 = W2_r
    int g = (b - PREP_B1) * 256 + t;
    int n = g >> 10;
    int kg = g & 1023;
    const float* s = (n < 256) ? (W2l + (size_t)n * 4096 + kg * 4)
                               : (W2r + (size_t)(n - 256) * 4096 + kg * 4);
    float4 v = *(const float4*)s;
    ushort4 p = {f2bf(v.x), f2bf(v.y), f2bf(v.z), f2bf(v.w)};
    ((ushort4*)w2cat)[g] = p;
  } else if (b < PREP_B3) {  // x -> bf16, [10000][1024]
    int g = (b - PREP_B2) * 256 + t;
    int i = g >> 8;
    int kg = g & 255;
    float4 v = ((const float4*)(x + (size_t)i * IN_DIM))[kg];
    ushort4 p = {f2bf(v.x), f2bf(v.y), f2bf(v.z), f2bf(v.w)};
    ((ushort4*)(x_bf + (size_t)i * IN_DIM))[kg] = p;
  } else {  // degree count
    int e = (b - PREP_B3) * 256 + t;
    if (e < NE) atomicAdd(&deg[dst[e]], 1);
  }
}

// one-block exclusive scan over NN degrees -> offs[0..NN] and cursor copy cur[]
__global__ __launch_bounds__(256) void scan_kernel(const int* __restrict__ deg,
                                                   int* __restrict__ offs,
                                                   int* __restrict__ cur) {
  __shared__ int part[256];
  constexpr int NPT = 40;  // 256*40 = 10240 >= NN
  int t = threadIdx.x;
  int base = t * NPT;
  int s = 0;
  for (int j = 0; j < NPT; ++j) {
    int n = base + j;
    s += (n < NN) ? deg[n] : 0;
  }
  part[t] = s;
  __syncthreads();
  for (int o = 1; o < 256; o <<= 1) {  // Hillis-Steele inclusive scan
    int v = (t >= o) ? part[t - o] : 0;
    __syncthreads();
    part[t] += v;
    __syncthreads();
  }
  int pre = (t > 0) ? part[t - 1] : 0;
  for (int j = 0; j < NPT; ++j) {
    int n = base + j;
    if (n < NN) {
      offs[n] = pre;
      cur[n] = pre;
      pre += deg[n];
    }
  }
  if (t == 255) offs[NN] = part[255];  // == NE
}

// bin edges: csr[cur[dst]++] = src  (cur pre-seeded with offs by scan)
__global__ void bin_kernel(const int* __restrict__ src, const int* __restrict__ dst,
                           int* __restrict__ cur, int* __restrict__ csr) {
  int e = blockIdx.x * 256 + threadIdx.x;
  if (e < NE) {
    int p = atomicAdd(&cur[dst[e]], 1);
    csr[p] = src[e];
  }
}

// ---------------- layer-1 gather (bf16 source): A1 = [mean_agg(x) | x] ----------------
// grid = M_PAD blocks; rows >= NN are zero pad (absorbs the pad memset).
__global__ __launch_bounds__(256) void gather1_kernel(const unsigned short* __restrict__ x_bf,
                                                      const int* __restrict__ offs,
                                                      const int* __restrict__ csr,
                                                      unsigned short* __restrict__ A1) {
  int i = blockIdx.x;
  int t = threadIdx.x;  // 256 threads x ushort4 = 1024 bf16 = one row
  unsigned short* row = A1 + (size_t)i * 2048;
  if (i >= NN) {
    ushort4 z = {0, 0, 0, 0};
    ((ushort4*)row)[t] = z;
    ((ushort4*)(row + 1024))[t] = z;
    return;
  }
  int beg = offs[i], end = offs[i + 1];
  float4 a0 = {0.f, 0.f, 0.f, 0.f}, a1 = {0.f, 0.f, 0.f, 0.f};
  int j = beg;
  for (; j + 2 <= end; j += 2) {
    int s0 = __builtin_amdgcn_readfirstlane(csr[j]);
    int s1 = __builtin_amdgcn_readfirstlane(csr[j + 1]);
    ushort4 u0 = ((const ushort4*)(x_bf + (size_t)s0 * IN_DIM))[t];
    ushort4 u1 = ((const ushort4*)(x_bf + (size_t)s1 * IN_DIM))[t];
    a0.x += bf2f(u0.x); a0.y += bf2f(u0.y); a0.z += bf2f(u0.z); a0.w += bf2f(u0.w);
    a1.x += bf2f(u1.x); a1.y += bf2f(u1.y); a1.z += bf2f(u1.z); a1.w += bf2f(u1.w);
  }
  if (j < end) {
    int s0 = __builtin_amdgcn_readfirstlane(csr[j]);
    ushort4 u0 = ((const ushort4*)(x_bf + (size_t)s0 * IN_DIM))[t];
    a0.x += bf2f(u0.x); a0.y += bf2f(u0.y); a0.z += bf2f(u0.z); a0.w += bf2f(u0.w);
  }
  float inv = 1.0f / (float)max(end - beg, 1);
  ushort4 ub = ((const ushort4*)(x_bf + (size_t)i * IN_DIM))[t];
  ushort4 pa = {f2bf((a0.x + a1.x) * inv), f2bf((a0.y + a1.y) * inv),
                f2bf((a0.z + a1.z) * inv), f2bf((a0.w + a1.w) * inv)};
  ((ushort4*)row)[t] = pa;           // cols 0..1023  = mean
  ((ushort4*)(row + 1024))[t] = ub;  // cols 1024..2047 = x
}

// ---------------- bf16 MFMA GEMM, templated BM/BN/BK/split-K/wave-layout ----------------
// C[M_PAD,N] = A[M_PAD,K] * Bt[N,K]^T. 4 waves; NWY = waves along n:
//   NWY=2 -> 2x2 (each wave BM/2 x 64), NWY=4 -> 1x4 (each wave BM x 64, BN=256).
// Block mapping: Triton-style GM-grouped swizzle (GM=1 degenerates to pn-fastest).
// XCD-banded m-major sweep measured 2.5x FETCH regression (R6) — do not revisit.
// Split-K: KSPLIT slabs in grid.y, each covers K/KSPLIT; EPI 3 writes bf16 partial.
// LDS chunk swizzle: physical 16B chunk p of row r holds logical chunk p ^ (r&7);
// ds_read_b128 at p=(kk*4+quad)^(l16&7) -> 2-way bank aliasing (free, measured 0 conflicts).
// EPI 1: C0 = bf16 [M][N], relu(acc + bias)             (layer 1)
// EPI 3: C0 = bf16 partial [KSPLIT][M][N] at grid.y     (layer 2, reduced later)
template <int BM, int BN, int BK, int K, int KSPLIT, int N, int NUMM, int NUMN, int GM,
          int EPI, int NWY>
__global__ __launch_bounds__(256) void gemm_kernel(const unsigned short* __restrict__ A,
                                                   const unsigned short* __restrict__ Bt,
                                                   const float* __restrict__ bias,
                                                   void* __restrict__ C0out) {
  constexpr int MGR = 4 / NWY;            // waves along m
  constexpr int MI = BM / 16 / MGR;       // 16-row tiles per wave
  constexpr int NI = 4;                   // 16-col tiles per wave (BN = NWY*64)
  constexpr int CPR = BK / 8;             // 16B chunks per LDS row
  constexpr int SA = BM * CPR / 256;      // staging rounds for A (256 thr x 16B)
  constexpr int SB = BN * CPR / 256;
  constexpr int KK = BK / 32;             // MFMA k-steps per tile
  constexpr int KS = K / KSPLIT;          // K range per split
  __shared__ unsigned short Asm[BM * BK];
  __shared__ unsigned short Bsm[BN * BK];

  // grouped swizzle on grid.x
  constexpr int NPG = GM * NUMN;
  const int pid = blockIdx.x;
  const int gid = pid / NPG;
  const int first_m = gid * GM;
  const int sz = (NUMM - first_m < GM) ? (NUMM - first_m) : GM;
  const int local = pid % NPG;
  const int pm = first_m + local % sz;
  const int pn = local / sz;
  const int koff = (KSPLIT > 1) ? (int)blockIdx.y * KS : 0;

  const int tid = threadIdx.x;
  const int lane = tid & 63;
  const int wave = tid >> 6;
  const int quad = lane >> 4;
  const int l16 = lane & 15;
  const int wm = (wave % MGR) * (BM / MGR);
  const int wn = (wave / MGR) * 64;
  const long tm0 = (long)pm * BM;
  const long tn0 = (long)pn * BN;

  f32x4 acc[MI][NI];
#pragma unroll
  for (int i = 0; i < MI; ++i)
#pragma unroll
    for (int j = 0; j < NI; ++j) acc[i][j] = (f32x4){0.f, 0.f, 0.f, 0.f};

  // staging: chunk c = s*256 + tid; row r = c / CPR; physical slot = c % CPR;
  // source logical chunk g = slot ^ (r & 7)  -> global col g*8
  const unsigned short* aSrc[SA];
  unsigned short* aDst[SA];
  const unsigned short* bSrc[SB];
  unsigned short* bDst[SB];
#pragma unroll
  for (int s = 0; s < SA; ++s) {
    int c = s * 256 + wave * 64 + lane;
    int r = c / CPR;
    int g = (c % CPR) ^ (r & 7);
    aSrc[s] = A + (size_t)(tm0 + r) * K + koff + g * 8;
    aDst[s] = Asm + s * 2048 + wave * 512;  // wave-uniform base
  }
#pragma unroll
  for (int s = 0; s < SB; ++s) {
    int c = s * 256 + wave * 64 + lane;
    int r = c / CPR;
    int g = (c % CPR) ^ (r & 7);
    bSrc[s] = Bt + (size_t)(tn0 + r) * K + koff + g * 8;
    bDst[s] = Bsm + s * 2048 + wave * 512;
  }

  const int l7 = l16 & 7;

  for (int k0 = 0; k0 < KS; k0 += BK) {
#pragma unroll
    for (int s = 0; s < SA; ++s) ld_lds16(aSrc[s] + k0, aDst[s]);
#pragma unroll
    for (int s = 0; s < SB; ++s) ld_lds16(bSrc[s] + k0, bDst[s]);
    __syncthreads();  // drains vmcnt -> LDS tiles complete

#pragma unroll
    for (int kk = 0; kk < KK; ++kk) {
      const int p = (kk * 4 + quad) ^ l7;  // physical chunk for this frag
      bf16x8 af[MI], bv[NI];
#pragma unroll
      for (int i = 0; i < MI; ++i) {
        int ra = wm + i * 16 + l16;
        af[i] = *(const bf16x8*)(Asm + ra * BK + p * 8);
      }
#pragma unroll
      for (int j = 0; j < NI; ++j) {
        int rb = wn + j * 16 + l16;
        bv[j] = *(const bf16x8*)(Bsm + rb * BK + p * 8);
      }
#pragma unroll
      for (int i = 0; i < MI; ++i)
#pragma unroll
        for (int j = 0; j < NI; ++j)
          acc[i][j] = __builtin_amdgcn_mfma_f32_16x16x32_bf16(af[i], bv[j], acc[i][j], 0, 0, 0);
    }
    __syncthreads();  // LDS reads done before next stage overwrites
  }

  // epilogue: C/D layout col = lane&15, row = quad*4 + reg
  if (EPI == 1) {
    unsigned short* C = (unsigned short*)C0out;
#pragma unroll
    for (int i = 0; i < MI; ++i) {
      long m0 = tm0 + wm + i * 16 + quad * 4;
#pragma unroll
      for (int j = 0; j < NI; ++j) {
        int n = (int)tn0 + wn + j * 16 + l16;
        float bvs = bias[n];
#pragma unroll
        for (int r = 0; r < 4; ++r) {
          float v = acc[i][j][r] + bvs;
          v = fmaxf(v, 0.0f);
          C[(size_t)(m0 + r) * N + n] = f2bf(v);
        }
      }
    }
  } else {  // EPI == 3: bf16 partial, slab per grid.y
    unsigned short* C = (unsigned short*)C0out + (size_t)blockIdx.y * NUMM * BM * N;
#pragma unroll
    for (int i = 0; i < MI; ++i) {
      long m0 = tm0 + wm + i * 16 + quad * 4;
#pragma unroll
      for (int j = 0; j < NI; ++j) {
        int n = (int)tn0 + wn + j * 16 + l16;
#pragma unroll
        for (int r = 0; r < 4; ++r) C[(size_t)(m0 + r) * N + n] = f2bf(acc[i][j][r]);
      }
    }
  }
}

// ---------------- split-K reduce: pl/pr = P0 + P1 ----------------
// P = [2][M_PAD][512] bf16. grid = M_PAD/4 blocks, 256 threads; thread handles 8 cols
// of one row: row = blk*4 + tid/64, col = (tid&63)*8. cols<256 -> pl bf16; else pr f32.
__global__ __launch_bounds__(256) void reduce2_kernel(const unsigned short* __restrict__ P,
                                                      unsigned short* __restrict__ pl,
                                                      float* __restrict__ pr) {
  int tid = threadIdx.x;
  size_t row = (size_t)blockIdx.x * 4 + (tid >> 6);
  int col = (tid & 63) * 8;
  size_t base = row * 512 + col;
  uint4 a = *(const uint4*)(P + base);
  uint4 b = *(const uint4*)(P + (size_t)M_PAD * 512 + base);
  float s[8];
  const unsigned int* aw = (const unsigned int*)&a;
  const unsigned int* bw = (const unsigned int*)&b;
#pragma unroll
  for (int j = 0; j < 4; ++j) {
    s[2 * j] = bf2f((unsigned short)(aw[j] & 0xffffu)) + bf2f((unsigned short)(bw[j] & 0xffffu));
    s[2 * j + 1] = bf2f((unsigned short)(aw[j] >> 16)) + bf2f((unsigned short)(bw[j] >> 16));
  }
  if (col < 256) {
    unsigned int o[4];
#pragma unroll
    for (int j = 0; j < 4; ++j)
      o[j] = (unsigned int)f2bf(s[2 * j]) | ((unsigned int)f2bf(s[2 * j + 1]) << 16);
    *(uint4*)(pl + row * 256 + col) = *(const uint4*)o;
  } else {
    float* d = pr + row * 256 + (col - 256);
    *(float4*)d = (float4){s[0], s[1], s[2], s[3]};
    *(float4*)(d + 4) = (float4){s[4], s[5], s[6], s[7]};
  }
}

// ---------------- layer-2 gather + bias + p_r + log_softmax (fused) ----------------
// 128 threads/block, thread t owns cols {2t, 2t+1}; p_l read as packed 2xbf16; edge loop x2.
__global__ __launch_bounds__(128) void gather2_final_kernel(const unsigned short* __restrict__ pl,
                                                            const float* __restrict__ pr,
                                                            const int* __restrict__ offs,
                                                            const int* __restrict__ csr,
                                                            const float* __restrict__ b2,
                                                            float* __restrict__ out) {
  int i = blockIdx.x;
  int t = threadIdx.x;  // 0..127
  int beg = offs[i], end = offs[i + 1];
  float a0 = 0.f, a1 = 0.f, c0 = 0.f, c1 = 0.f;
  int j = beg;
  for (; j + 2 <= end; j += 2) {
    int s0 = __builtin_amdgcn_readfirstlane(csr[j]);
    int s1 = __builtin_amdgcn_readfirstlane(csr[j + 1]);
    unsigned int u0 = ((const unsigned int*)(pl + (size_t)s0 * 256))[t];
    unsigned int u1 = ((const unsigned int*)(pl + (size_t)s1 * 256))[t];
    a0 += bf2f((unsigned short)(u0 & 0xffffu));
    a1 += bf2f((unsigned short)(u0 >> 16));
    c0 += bf2f((unsigned short)(u1 & 0xffffu));
    c1 += bf2f((unsigned short)(u1 >> 16));
  }
  if (j < end) {
    int s0 = __builtin_amdgcn_readfirstlane(csr[j]);
    unsigned int u0 = ((const unsigned int*)(pl + (size_t)s0 * 256))[t];
    a0 += bf2f((unsigned short)(u0 & 0xffffu));
    a1 += bf2f((unsigned short)(u0 >> 16));
  }
  float inv = 1.0f / (float)max(end - beg, 1);
  float2 bv = ((const float2*)b2)[t];
  float2 pv = ((const float2*)(pr + (size_t)i * 256))[t];
  float v0 = (a0 + c0) * inv + bv.x + pv.x;
  float v1 = (a1 + c1) * inv + bv.y + pv.y;

  __shared__ float sm[2], ss[2];
  int w = t >> 6;
  float m = fmaxf(v0, v1);
#pragma unroll
  for (int o = 32; o > 0; o >>= 1) m = fmaxf(m, __shfl_xor(m, o, 64));
  if ((t & 63) == 0) sm[w] = m;
  __syncthreads();
  m = fmaxf(sm[0], sm[1]);

  float s = __expf(v0 - m) + __expf(v1 - m);
#pragma unroll
  for (int o = 32; o > 0; o >>= 1) s += __shfl_xor(s, o, 64);
  if ((t & 63) == 0) ss[w] = s;
  __syncthreads();
  float ls = logf(ss[0] + ss[1]);

  float2 o2 = {v0 - m - ls, v1 - m - ls};
  ((float2*)(out + (size_t)i * OUTD))[t] = o2;
}

// ---------------- workspace layout (bytes) ----------------
// A1 region [41.4 MB] reused after GEMM1 as: P0/P1 bf16 [2][10112][512] (20.7 MB)
//   + pl bf16 [10112][256] (5.2 MB) + pr f32 [10112][256] (10.35 MB) = 36.3 MB  OK
static constexpr size_t OFF_A1 = 0;
static constexpr size_t OFF_W1 = OFF_A1 + (size_t)M_PAD * 2048 * 2;
static constexpr size_t OFF_HB = OFF_W1 + (size_t)HID * 2048 * 2;
static constexpr size_t OFF_W2 = OFF_HB + (size_t)M_PAD * HID * 2;
static constexpr size_t OFF_XBF = OFF_W2 - (size_t)NN * IN_DIM * 2;  // tail of h_b
static constexpr size_t OFF_DEG = OFF_W2 + (size_t)512 * HID * 2;
static constexpr size_t OFF_OFFS = OFF_DEG + (size_t)NN * 4;
static constexpr size_t OFF_CUR = OFF_OFFS + (size_t)(NN + 4) * 4;
static constexpr size_t OFF_CSR = OFF_CUR + (size_t)NN * 4;
static constexpr size_t OFF_P = OFF_A1;                               // [2][M_PAD][512] bf16
static constexpr size_t OFF_PL = OFF_P + (size_t)2 * M_PAD * 512 * 2;
static constexpr size_t OFF_PR = OFF_PL + (size_t)M_PAD * 256 * 2;

extern "C" void kernel_launch(void* const* d_in, const int* in_sizes, int n_in,
                              void* d_out, int out_size, void* d_ws, size_t ws_size,
                              hipStream_t stream) {
  const float* x = (const float*)d_in[0];
  const int* ei = (const int*)d_in[1];
  const int* src = ei;
  const int* dst = ei + NE;
  const float* W1_l = (const float*)d_in[2];
  const float* b1_l = (const float*)d_in[3];
  const float* W1_r = (const float*)d_in[4];
  const float* W2_l = (const float*)d_in[5];
  const float* b2_l = (const float*)d_in[6];
  const float* W2_r = (const float*)d_in[7];
  float* out = (float*)d_out;

  char* ws = (char*)d_ws;
  unsigned short* A1 = (unsigned short*)(ws + OFF_A1);
  unsigned short* w1cat = (unsigned short*)(ws + OFF_W1);
  unsigned short* h_b = (unsigned short*)(ws + OFF_HB);
  unsigned short* x_bf = (unsigned short*)(ws + OFF_XBF);
  unsigned short* w2cat = (unsigned short*)(ws + OFF_W2);
  int* deg = (int*)(ws + OFF_DEG);
  int* offs = (int*)(ws + OFF_OFFS);
  int* cur = (int*)(ws + OFF_CUR);
  int* csr = (int*)(ws + OFF_CSR);
  unsigned short* P = (unsigned short*)(ws + OFF_P);
  unsigned short* pl = (unsigned short*)(ws + OFF_PL);
  float* pr = (float*)(ws + OFF_PR);

  // zero degree counters (ws is poisoned 0xAA before every call)
  hipMemsetAsync(deg, 0, (size_t)NN * 4, stream);

  // fused prep: weight converts + x->bf16 + degree count
  prep_kernel<<<PREP_NB, 256, 0, stream>>>(W1_l, W1_r, W2_l, W2_r, x, dst,
                                           w1cat, w2cat, x_bf, deg);
  scan_kernel<<<1, 256, 0, stream>>>(deg, offs, cur);
  bin_kernel<<<(NE + 255) / 256, 256, 0, stream>>>(src, dst, cur, csr);

  // A1 = [mean | x] bf16 via CSR gather (no atomics); rows >= NN zeroed here
  gather1_kernel<<<M_PAD, 256, 0, stream>>>(x_bf, offs, csr, A1);

  // h = relu(A1 @ w1cat^T + b1)  -> bf16 [10112][4096]; BK=64, GM=32 grouped (R5/R8 config)
  gemm_kernel<128, 128, 64, 2048, 1, 4096, 79, 32, 32, 1, 2>
      <<<79 * 32, 256, 0, stream>>>(A1, w1cat, b1_l, h_b);
  // split-K=2, BN=256 (halves A re-reads — GEMM2 is A-L3-BW-bound):
  // P[s] = h[:, s*2048:(s+1)*2048] @ w2cat[:, same]^T -> bf16 [2][10112][512]
  gemm_kernel<64, 256, 64, 4096, 2, 512, 158, 2, 1, 3, 4>
      <<<dim3(158 * 2, 2), 256, 0, stream>>>(h_b, w2cat, nullptr, P);
  // pl/pr = P0 + P1  (pl bf16 [M][256], pr f32 [M][256])
  reduce2_kernel<<<M_PAD / 4, 256, 0, stream>>>(P, pl, pr);

  // mean of p_l over in-edges + bias + p_r, then log_softmax
  gather2_final_kernel<<<NN, 128, 0, stream>>>(pl, pr, offs, csr, b2_l, out);
}

// Round 10
// 437.681 us; speedup vs baseline: 1.1061x; 1.0088x over previous
//
#include <hip/hip_runtime.h>
#include <cstdint>
#include <cstddef>

#define DEVINL __device__ __forceinline__

typedef __bf16 bf16x8 __attribute__((ext_vector_type(8)));
typedef float f32x4 __attribute__((ext_vector_type(4)));

static constexpr int NN = 10000;     // nodes
static constexpr int NE = 80000;     // edges
static constexpr int IN_DIM = 1024;
static constexpr int HID = 4096;
static constexpr int OUTD = 256;
static constexpr int M_PAD = 10112;  // 79*128 (also 158*64)

// fp32 -> bf16 round-nearest-even
DEVINL unsigned short f2bf(float f) {
  unsigned int u = __builtin_bit_cast(unsigned int, f);
  u += 0x7fffu + ((u >> 16) & 1u);
  return (unsigned short)(u >> 16);
}
DEVINL float bf2f(unsigned short h) {
  unsigned int u = ((unsigned int)h) << 16;
  return __builtin_bit_cast(float, u);
}

// async global->LDS, 16B per lane; LDS dest is wave-uniform base + lane*16
DEVINL void ld_lds16(const void* g, void* l) {
  __builtin_amdgcn_global_load_lds(
      (const __attribute__((address_space(1))) unsigned int*)g,
      (__attribute__((address_space(3))) unsigned int*)l, 16, 0, 0);
}

// ---------------- fused prep: conv_w1 + conv_w2 + x->bf16 + degree count ----------------
static constexpr int PREP_B1 = 8192;
static constexpr int PREP_B2 = PREP_B1 + 2048;
static constexpr int PREP_B3 = PREP_B2 + 10000;
static constexpr int PREP_NB = PREP_B3 + 313;

__global__ __launch_bounds__(256) void prep_kernel(
    const float* __restrict__ W1l, const float* __restrict__ W1r,
    const float* __restrict__ W2l, const float* __restrict__ W2r,
    const float* __restrict__ x, const int* __restrict__ dst,
    unsigned short* __restrict__ w1cat, unsigned short* __restrict__ w2cat,
    unsigned short* __restrict__ x_bf, int* __restrict__ deg) {
  int b = blockIdx.x;
  int t = threadIdx.x;
  if (b < PREP_B1) {  // w1cat [4096][2048]: row n = [W1_l row n | W1_r row n]
    int g = b * 256 + t;
    int n = g >> 9;
    int kg = g & 511;
    const float* s = (kg < 256) ? (W1l + (size_t)n * 1024 + kg * 4)
                                : (W1r + (size_t)n * 1024 + (kg - 256) * 4);
    float4 v = *(const float4*)s;
    ushort4 p = {f2bf(v.x), f2bf(v.y), f2bf(v.z), f2bf(v.w)};
    ((ushort4*)w1cat)[g] = p;
  } else if (b < PREP_B2) {  // w2cat [512][4096]: rows 0..255 = W2_l, 256..511 = W2_r
    int g = (b - PREP_B1) * 256 + t;
    int n = g >> 10;
    int kg = g & 1023;
    const float* s = (n < 256) ? (W2l + (size_t)n * 4096 + kg * 4)
                               : (W2r + (size_t)(n - 256) * 4096 + kg * 4);
    float4 v = *(const float4*)s;
    ushort4 p = {f2bf(v.x), f2bf(v.y), f2bf(v.z), f2bf(v.w)};
    ((ushort4*)w2cat)[g] = p;
  } else if (b < PREP_B3) {  // x -> bf16, [10000][1024]
    int g = (b - PREP_B2) * 256 + t;
    int i = g >> 8;
    int kg = g & 255;
    float4 v = ((const float4*)(x + (size_t)i * IN_DIM))[kg];
    ushort4 p = {f2bf(v.x), f2bf(v.y), f2bf(v.z), f2bf(v.w)};
    ((ushort4*)(x_bf + (size_t)i * IN_DIM))[kg] = p;
  } else {  // degree count
    int e = (b - PREP_B3) * 256 + t;
    if (e < NE) atomicAdd(&deg[dst[e]], 1);
  }
}

// one-block exclusive scan over NN degrees -> offs[0..NN] and cursor copy cur[]
__global__ __launch_bounds__(1024) void scan_kernel(const int* __restrict__ deg,
                                                    int* __restrict__ offs,
                                                    int* __restrict__ cur) {
  __shared__ int part[1024];
  constexpr int NPT = 10;  // 1024*10 = 10240 >= NN
  int t = threadIdx.x;
  int base = t * NPT;
  int s = 0;
  for (int j = 0; j < NPT; ++j) {
    int n = base + j;
    s += (n < NN) ? deg[n] : 0;
  }
  part[t] = s;
  __syncthreads();
  for (int o = 1; o < 1024; o <<= 1) {  // Hillis-Steele inclusive scan
    int v = (t >= o) ? part[t - o] : 0;
    __syncthreads();
    part[t] += v;
    __syncthreads();
  }
  int pre = (t > 0) ? part[t - 1] : 0;
  for (int j = 0; j < NPT; ++j) {
    int n = base + j;
    if (n < NN) {
      offs[n] = pre;
      cur[n] = pre;
      pre += deg[n];
    }
  }
  if (t == 1023) offs[NN] = part[1023];  // == NE
}

// bin edges: csr[cur[dst]++] = src  (cur pre-seeded with offs by scan)
__global__ void bin_kernel(const int* __restrict__ src, const int* __restrict__ dst,
                           int* __restrict__ cur, int* __restrict__ csr) {
  int e = blockIdx.x * 256 + threadIdx.x;
  if (e < NE) {
    int p = atomicAdd(&cur[dst[e]], 1);
    csr[p] = src[e];
  }
}

// ---------------- layer-1 gather (bf16 source): A1 = mean_agg(x) only ----------------
// GEMM1 reads x_bf directly for the K>=1024 half, so no x copy here.
// grid = M_PAD blocks; blocks >= NN zero the A1 AND x_bf pad rows.
__global__ __launch_bounds__(256) void gather1_kernel(unsigned short* __restrict__ x_bf,
                                                      const int* __restrict__ offs,
                                                      const int* __restrict__ csr,
                                                      unsigned short* __restrict__ A1) {
  int i = blockIdx.x;
  int t = threadIdx.x;  // 256 threads x ushort4 = 1024 bf16 = one row
  unsigned short* row = A1 + (size_t)i * 1024;
  if (i >= NN) {
    ushort4 z = {0, 0, 0, 0};
    ((ushort4*)row)[t] = z;
    ((ushort4*)(x_bf + (size_t)i * 1024))[t] = z;
    return;
  }
  int beg = offs[i], end = offs[i + 1];
  float4 a0 = {0.f, 0.f, 0.f, 0.f}, a1 = {0.f, 0.f, 0.f, 0.f};
  int j = beg;
  for (; j + 2 <= end; j += 2) {
    int s0 = __builtin_amdgcn_readfirstlane(csr[j]);
    int s1 = __builtin_amdgcn_readfirstlane(csr[j + 1]);
    ushort4 u0 = ((const ushort4*)(x_bf + (size_t)s0 * IN_DIM))[t];
    ushort4 u1 = ((const ushort4*)(x_bf + (size_t)s1 * IN_DIM))[t];
    a0.x += bf2f(u0.x); a0.y += bf2f(u0.y); a0.z += bf2f(u0.z); a0.w += bf2f(u0.w);
    a1.x += bf2f(u1.x); a1.y += bf2f(u1.y); a1.z += bf2f(u1.z); a1.w += bf2f(u1.w);
  }
  if (j < end) {
    int s0 = __builtin_amdgcn_readfirstlane(csr[j]);
    ushort4 u0 = ((const ushort4*)(x_bf + (size_t)s0 * IN_DIM))[t];
    a0.x += bf2f(u0.x); a0.y += bf2f(u0.y); a0.z += bf2f(u0.z); a0.w += bf2f(u0.w);
  }
  float inv = 1.0f / (float)max(end - beg, 1);
  ushort4 pa = {f2bf((a0.x + a1.x) * inv), f2bf((a0.y + a1.y) * inv),
                f2bf((a0.z + a1.z) * inv), f2bf((a0.w + a1.w) * inv)};
  ((ushort4*)row)[t] = pa;
}

// ---------------- bf16 MFMA GEMM, templated BM/BN/BK/split-K/wave-layout ----------------
// C[M_PAD,N] = A[M_PAD,K] * Bt[N,K]^T. 4 waves; NWY = waves along n:
//   NWY=2 -> 2x2 (each wave BM/2 x 64), NWY=4 -> 1x4 (each wave BM x 64, BN=256).
// ASPLIT: A is two [M][K/2] buffers (A for k<K/2, A2 for k>=K/2), both row-stride K/2 —
//   lets GEMM1 read the mean block and x_bf directly without a concatenated copy.
// Block mapping: Triton-style GM-grouped swizzle. XCD-banded m-major sweep measured
// 2.5x FETCH regression (R6) — do not revisit.
// Split-K: KSPLIT slabs in grid.y, each covers K/KSPLIT; EPI 3 writes bf16 partial.
// LDS chunk swizzle: physical 16B chunk p of row r holds logical chunk p ^ (r&7);
// ds_read_b128 at p=(kk*4+quad)^(l16&7) -> 2-way bank aliasing (free, measured 0 conflicts).
// EPI 1: C0 = bf16 [M][N], relu(acc + bias)             (layer 1)
// EPI 3: C0 = bf16 partial [KSPLIT][M][N] at grid.y     (layer 2, summed in gather2)
template <int BM, int BN, int BK, int K, int KSPLIT, int N, int NUMM, int NUMN, int GM,
          int EPI, int NWY, bool ASPLIT>
__global__ __launch_bounds__(256) void gemm_kernel(const unsigned short* __restrict__ A,
                                                   const unsigned short* __restrict__ A2,
                                                   const unsigned short* __restrict__ Bt,
                                                   const float* __restrict__ bias,
                                                   void* __restrict__ C0out) {
  constexpr int MGR = 4 / NWY;            // waves along m
  constexpr int MI = BM / 16 / MGR;       // 16-row tiles per wave
  constexpr int NI = 4;                   // 16-col tiles per wave (BN = NWY*64)
  constexpr int CPR = BK / 8;             // 16B chunks per LDS row
  constexpr int SA = BM * CPR / 256;      // staging rounds for A (256 thr x 16B)
  constexpr int SB = BN * CPR / 256;
  constexpr int KK = BK / 32;             // MFMA k-steps per tile
  constexpr int KS = K / KSPLIT;          // K range per split
  constexpr int AS = ASPLIT ? K / 2 : K;  // A row stride
  __shared__ unsigned short Asm[BM * BK];
  __shared__ unsigned short Bsm[BN * BK];

  // grouped swizzle on grid.x
  constexpr int NPG = GM * NUMN;
  const int pid = blockIdx.x;
  const int gid = pid / NPG;
  const int first_m = gid * GM;
  const int sz = (NUMM - first_m < GM) ? (NUMM - first_m) : GM;
  const int local = pid % NPG;
  const int pm = first_m + local % sz;
  const int pn = local / sz;
  const int koff = (KSPLIT > 1) ? (int)blockIdx.y * KS : 0;

  const int tid = threadIdx.x;
  const int lane = tid & 63;
  const int wave = tid >> 6;
  const int quad = lane >> 4;
  const int l16 = lane & 15;
  const int wm = (wave % MGR) * (BM / MGR);
  const int wn = (wave / MGR) * 64;
  const long tm0 = (long)pm * BM;
  const long tn0 = (long)pn * BN;

  f32x4 acc[MI][NI];
#pragma unroll
  for (int i = 0; i < MI; ++i)
#pragma unroll
    for (int j = 0; j < NI; ++j) acc[i][j] = (f32x4){0.f, 0.f, 0.f, 0.f};

  // staging: chunk c = s*256 + tid; row r = c / CPR; physical slot = c % CPR;
  // source logical chunk g = slot ^ (r & 7)  -> global col g*8
  size_t aOff[SA];
  unsigned short* aDst[SA];
  const unsigned short* bSrc[SB];
  unsigned short* bDst[SB];
#pragma unroll
  for (int s = 0; s < SA; ++s) {
    int c = s * 256 + wave * 64 + lane;
    int r = c / CPR;
    int g = (c % CPR) ^ (r & 7);
    aOff[s] = (size_t)(tm0 + r) * AS + koff + g * 8;
    aDst[s] = Asm + s * 2048 + wave * 512;  // wave-uniform base
  }
#pragma unroll
  for (int s = 0; s < SB; ++s) {
    int c = s * 256 + wave * 64 + lane;
    int r = c / CPR;
    int g = (c % CPR) ^ (r & 7);
    bSrc[s] = Bt + (size_t)(tn0 + r) * K + koff + g * 8;
    bDst[s] = Bsm + s * 2048 + wave * 512;
  }

  const int l7 = l16 & 7;

  for (int k0 = 0; k0 < KS; k0 += BK) {
    const unsigned short* ab = (!ASPLIT || k0 < K / 2) ? A : A2;
    const int ka = ASPLIT ? (k0 & (K / 2 - 1)) : k0;
#pragma unroll
    for (int s = 0; s < SA; ++s) ld_lds16(ab + aOff[s] + ka, aDst[s]);
#pragma unroll
    for (int s = 0; s < SB; ++s) ld_lds16(bSrc[s] + k0, bDst[s]);
    __syncthreads();  // drains vmcnt -> LDS tiles complete

#pragma unroll
    for (int kk = 0; kk < KK; ++kk) {
      const int p = (kk * 4 + quad) ^ l7;  // physical chunk for this frag
      bf16x8 af[MI], bv[NI];
#pragma unroll
      for (int i = 0; i < MI; ++i) {
        int ra = wm + i * 16 + l16;
        af[i] = *(const bf16x8*)(Asm + ra * BK + p * 8);
      }
#pragma unroll
      for (int j = 0; j < NI; ++j) {
        int rb = wn + j * 16 + l16;
        bv[j] = *(const bf16x8*)(Bsm + rb * BK + p * 8);
      }
#pragma unroll
      for (int i = 0; i < MI; ++i)
#pragma unroll
        for (int j = 0; j < NI; ++j)
          acc[i][j] = __builtin_amdgcn_mfma_f32_16x16x32_bf16(af[i], bv[j], acc[i][j], 0, 0, 0);
    }
    __syncthreads();  // LDS reads done before next stage overwrites
  }

  // epilogue: C/D layout col = lane&15, row = quad*4 + reg
  if (EPI == 1) {
    unsigned short* C = (unsigned short*)C0out;
#pragma unroll
    for (int i = 0; i < MI; ++i) {
      long m0 = tm0 + wm + i * 16 + quad * 4;
#pragma unroll
      for (int j = 0; j < NI; ++j) {
        int n = (int)tn0 + wn + j * 16 + l16;
        float bvs = bias[n];
#pragma unroll
        for (int r = 0; r < 4; ++r) {
          float v = acc[i][j][r] + bvs;
          v = fmaxf(v, 0.0f);
          C[(size_t)(m0 + r) * N + n] = f2bf(v);
        }
      }
    }
  } else {  // EPI == 3: bf16 partial, slab per grid.y
    unsigned short* C = (unsigned short*)C0out + (size_t)blockIdx.y * NUMM * BM * N;
#pragma unroll
    for (int i = 0; i < MI; ++i) {
      long m0 = tm0 + wm + i * 16 + quad * 4;
#pragma unroll
      for (int j = 0; j < NI; ++j) {
        int n = (int)tn0 + wn + j * 16 + l16;
#pragma unroll
        for (int r = 0; r < 4; ++r) C[(size_t)(m0 + r) * N + n] = f2bf(acc[i][j][r]);
      }
    }
  }
}

// ---------------- layer-2 gather + bias + p_r + log_softmax (fused, reads split-K P) ----
// P = [2][M_PAD][512] bf16 (cols 0..255 = p_l partial, 256..511 = p_r partial).
// 128 threads/block, thread t owns cols {2t, 2t+1}; edge loop x2 unrolled (4 loads in flight).
__global__ __launch_bounds__(128) void gather2_final_kernel(const unsigned short* __restrict__ P,
                                                            const int* __restrict__ offs,
                                                            const int* __restrict__ csr,
                                                            const float* __restrict__ b2,
                                                            float* __restrict__ out) {
  int i = blockIdx.x;
  int t = threadIdx.x;  // 0..127
  const unsigned short* P1 = P + (size_t)M_PAD * 512;
  int beg = offs[i], end = offs[i + 1];
  float a0 = 0.f, a1 = 0.f, c0 = 0.f, c1 = 0.f;
  int j = beg;
  for (; j + 2 <= end; j += 2) {
    int s0 = __builtin_amdgcn_readfirstlane(csr[j]);
    int s1 = __builtin_amdgcn_readfirstlane(csr[j + 1]);
    unsigned int u0 = ((const unsigned int*)(P + (size_t)s0 * 512))[t];
    unsigned int w0 = ((const unsigned int*)(P1 + (size_t)s0 * 512))[t];
    unsigned int u1 = ((const unsigned int*)(P + (size_t)s1 * 512))[t];
    unsigned int w1 = ((const unsigned int*)(P1 + (size_t)s1 * 512))[t];
    a0 += bf2f((unsigned short)(u0 & 0xffffu)) + bf2f((unsigned short)(w0 & 0xffffu));
    a1 += bf2f((unsigned short)(u0 >> 16)) + bf2f((unsigned short)(w0 >> 16));
    c0 += bf2f((unsigned short)(u1 & 0xffffu)) + bf2f((unsigned short)(w1 & 0xffffu));
    c1 += bf2f((unsigned short)(u1 >> 16)) + bf2f((unsigned short)(w1 >> 16));
  }
  if (j < end) {
    int s0 = __builtin_amdgcn_readfirstlane(csr[j]);
    unsigned int u0 = ((const unsigned int*)(P + (size_t)s0 * 512))[t];
    unsigned int w0 = ((const unsigned int*)(P1 + (size_t)s0 * 512))[t];
    a0 += bf2f((unsigned short)(u0 & 0xffffu)) + bf2f((unsigned short)(w0 & 0xffffu));
    a1 += bf2f((unsigned short)(u0 >> 16)) + bf2f((unsigned short)(w0 >> 16));
  }
  float inv = 1.0f / (float)max(end - beg, 1);
  float2 bv = ((const float2*)b2)[t];
  // self p_r term: cols 256+2t, 257+2t of both partial slabs
  unsigned int su = ((const unsigned int*)(P + (size_t)i * 512))[128 + t];
  unsigned int sw = ((const unsigned int*)(P1 + (size_t)i * 512))[128 + t];
  float pv0 = bf2f((unsigned short)(su & 0xffffu)) + bf2f((unsigned short)(sw & 0xffffu));
  float pv1 = bf2f((unsigned short)(su >> 16)) + bf2f((unsigned short)(sw >> 16));
  float v0 = (a0 + c0) * inv + bv.x + pv0;
  float v1 = (a1 + c1) * inv + bv.y + pv1;

  __shared__ float sm[2], ss[2];
  int w = t >> 6;
  float m = fmaxf(v0, v1);
#pragma unroll
  for (int o = 32; o > 0; o >>= 1) m = fmaxf(m, __shfl_xor(m, o, 64));
  if ((t & 63) == 0) sm[w] = m;
  __syncthreads();
  m = fmaxf(sm[0], sm[1]);

  float s = __expf(v0 - m) + __expf(v1 - m);
#pragma unroll
  for (int o = 32; o > 0; o >>= 1) s += __shfl_xor(s, o, 64);
  if ((t & 63) == 0) ss[w] = s;
  __syncthreads();
  float ls = logf(ss[0] + ss[1]);

  float2 o2 = {v0 - m - ls, v1 - m - ls};
  ((float2*)(out + (size_t)i * OUTD))[t] = o2;
}

// ---------------- workspace layout (bytes) ----------------
// A1 mean [10112][1024] bf16 = 20.7 MB   (after GEMM1: reused as P [2][10112][512] bf16)
// x_bf    [10112][1024] bf16 = 20.7 MB   (read by gather1 AND by GEMM1's K>=1024 half)
// w1cat [4096][2048] bf16 = 16.8 MB | h_b [10112][4096] bf16 = 82.8 MB | w2cat 4.2 MB
static constexpr size_t OFF_A1 = 0;
static constexpr size_t OFF_XBF = OFF_A1 + (size_t)M_PAD * 1024 * 2;
static constexpr size_t OFF_W1 = OFF_XBF + (size_t)M_PAD * 1024 * 2;
static constexpr size_t OFF_HB = OFF_W1 + (size_t)HID * 2048 * 2;
static constexpr size_t OFF_W2 = OFF_HB + (size_t)M_PAD * HID * 2;
static constexpr size_t OFF_DEG = OFF_W2 + (size_t)512 * HID * 2;
static constexpr size_t OFF_OFFS = OFF_DEG + (size_t)NN * 4;
static constexpr size_t OFF_CUR = OFF_OFFS + (size_t)(NN + 4) * 4;
static constexpr size_t OFF_CSR = OFF_CUR + (size_t)NN * 4;
static constexpr size_t OFF_P = OFF_A1;  // [2][M_PAD][512] bf16 = 20.7 MB, fits A1 region

extern "C" void kernel_launch(void* const* d_in, const int* in_sizes, int n_in,
                              void* d_out, int out_size, void* d_ws, size_t ws_size,
                              hipStream_t stream) {
  const float* x = (const float*)d_in[0];
  const int* ei = (const int*)d_in[1];
  const int* src = ei;
  const int* dst = ei + NE;
  const float* W1_l = (const float*)d_in[2];
  const float* b1_l = (const float*)d_in[3];
  const float* W1_r = (const float*)d_in[4];
  const float* W2_l = (const float*)d_in[5];
  const float* b2_l = (const float*)d_in[6];
  const float* W2_r = (const float*)d_in[7];
  float* out = (float*)d_out;

  char* ws = (char*)d_ws;
  unsigned short* A1 = (unsigned short*)(ws + OFF_A1);
  unsigned short* x_bf = (unsigned short*)(ws + OFF_XBF);
  unsigned short* w1cat = (unsigned short*)(ws + OFF_W1);
  unsigned short* h_b = (unsigned short*)(ws + OFF_HB);
  unsigned short* w2cat = (unsigned short*)(ws + OFF_W2);
  int* deg = (int*)(ws + OFF_DEG);
  int* offs = (int*)(ws + OFF_OFFS);
  int* cur = (int*)(ws + OFF_CUR);
  int* csr = (int*)(ws + OFF_CSR);
  unsigned short* P = (unsigned short*)(ws + OFF_P);

  // zero degree counters (ws is poisoned 0xAA before every call)
  hipMemsetAsync(deg, 0, (size_t)NN * 4, stream);

  // fused prep: weight converts + x->bf16 + degree count
  prep_kernel<<<PREP_NB, 256, 0, stream>>>(W1_l, W1_r, W2_l, W2_r, x, dst,
                                           w1cat, w2cat, x_bf, deg);
  scan_kernel<<<1, 1024, 0, stream>>>(deg, offs, cur);
  bin_kernel<<<(NE + 255) / 256, 256, 0, stream>>>(src, dst, cur, csr);

  // A1 = mean agg (bf16) via CSR gather; pad rows of A1 AND x_bf zeroed here
  gather1_kernel<<<M_PAD, 256, 0, stream>>>(x_bf, offs, csr, A1);

  // h = relu([A1 | x_bf] @ w1cat^T + b1) -> bf16 [10112][4096]; ASPLIT A, BK=64, GM=32
  gemm_kernel<128, 128, 64, 2048, 1, 4096, 79, 32, 32, 1, 2, true>
      <<<79 * 32, 256, 0, stream>>>(A1, x_bf, w1cat, b1_l, h_b);
  // split-K=2, BN=256: P[s] = h[:, s*2048:(s+1)*2048] @ w2cat[:, same]^T -> bf16 [2][M][512]
  gemm_kernel<64, 256, 64, 4096, 2, 512, 158, 2, 1, 3, 4, false>
      <<<dim3(158 * 2, 2), 256, 0, stream>>>(h_b, nullptr, w2cat, nullptr, P);

  // mean of p_l over in-edges + bias + p_r (both summed from split-K partials), log_softmax
  gather2_final_kernel<<<NN, 128, 0, stream>>>(P, offs, csr, b2_l, out);
}